// Round 3
// baseline (1178.718 us; speedup 1.0000x reference)
//
#include <hip/hip_runtime.h>

// ---------------------------------------------------------------------------
// RNNCell encoder: seq=512, batch=512, H=IN=300.
//   prep:   W_ih, W_hh -> bf16 zero-padded [320][320]; bias = b_ih+b_hh.
//   xproj:  xp[m][n] = in[m][:]*W_ih[n][:] + bias[n]  (bf16 out, stride 300)
//           BM=128, BN=320, BK=32 double-buffered, 1 barrier/iter,
//           B staged via global_load_lds (16B). launch_bounds(512,1): the
//           (512,2) cap forced <=128 VGPRs -> scratch spill (R2: ~520us).
//   recur:  32 WGs x 256 thr. D[n][b] = W_hh * h^T orientation.
//           KEY FIX vs R2: W_hh A-frags pinned in registers via opaque asm
//           (R2 compiler re-fetched 205 KB/WG/step from L2 -> 3040 cy/step,
//           L2-BW-bound). Raw s_barrier (lgkmcnt only) so xp prefetch loads
//           are never vmcnt(0)-drained at the per-step barrier.
// ---------------------------------------------------------------------------

typedef unsigned short u16;
typedef unsigned int   u32;
typedef __attribute__((ext_vector_type(8)))  short bf16x8;
typedef __attribute__((ext_vector_type(4)))  short s16x4;
typedef __attribute__((ext_vector_type(4)))  float f32x4;
typedef __attribute__((ext_vector_type(16))) float f32x16;
typedef __attribute__((ext_vector_type(2)))  unsigned int u32x2;
typedef __attribute__((ext_vector_type(4)))  unsigned int u32x4;

#define HID 300
#define KP  320
#define SEQ 512
#define BZ  512
#define MTOT (SEQ*BZ)

__device__ __forceinline__ u16 f2bf(float f) {
    u32 u = __float_as_uint(f);
    return (u16)((u + 0x7FFFu + ((u >> 16) & 1u)) >> 16);  // RNE
}
__device__ __forceinline__ float bf2f(u16 h) {
    return __uint_as_float((u32)h << 16);
}
__device__ __forceinline__ float tanh_fast(float x) {
    float e = __builtin_amdgcn_exp2f(x * 2.8853900817779268f);  // exp(2x)
    float r = __builtin_amdgcn_rcpf(e + 1.0f);
    return __builtin_fmaf(-2.0f, r, 1.0f);
}
__device__ __forceinline__ u32 pack2(float a, float b) {
    return (u32)f2bf(a) | ((u32)f2bf(b) << 16);
}
// Workgroup barrier WITHOUT vmcnt drain: LDS ordering only.
__device__ __forceinline__ void lds_barrier() {
    asm volatile("s_waitcnt lgkmcnt(0)\n\ts_barrier" ::: "memory");
}

// ---------------------------------------------------------------------------
__global__ void prep_kernel(const float* __restrict__ wih,
                            const float* __restrict__ whh,
                            const float* __restrict__ bih,
                            const float* __restrict__ bhh,
                            u16* __restrict__ wihp, u16* __restrict__ whhp,
                            float* __restrict__ bias) {
    int n = blockIdx.x, k = threadIdx.x;
    bool v = (n < HID) && (k < HID);
    int src = n * HID + k, dst = n * KP + k;
    wihp[dst] = v ? f2bf(wih[src]) : (u16)0;
    whhp[dst] = v ? f2bf(whh[src]) : (u16)0;
    if (k == 0) bias[n] = (n < HID) ? (bih[n] + bhh[n]) : 0.0f;
}

// ---------------------------------------------------------------------------
// Phase 1: xp = in @ W_ih^T + bias. 2048 WGs x 512 thr.
// LDS A layout (per buf): [kc16 0..1][m 0..127][16 el]   (4096 u16 = 8 KB)
// LDS B layout (per buf): [kc8 0..3][n 0..319][8 el]     (10240 u16 = 20 KB)
__global__ __launch_bounds__(512, 1) void xproj_kernel(
    const float* __restrict__ in, const u16* __restrict__ wihp,
    const float* __restrict__ bias, u16* __restrict__ xp) {
    __shared__ __align__(16) u16 As[2][4096];
    __shared__ __align__(16) u16 Bs[2][10240];

    const int tid = threadIdx.x;
    const int w = tid >> 6, l = tid & 63;
    const int mi = w & 3, ni = w >> 2;
    const int l31 = l & 31, l5 = l >> 5;
    const int m0 = blockIdx.x * 128;

    // staging roles
    const int sm = tid >> 2, skg = tid & 3;   // A: row, 8-k group

    f32x16 acc[5];
#pragma unroll
    for (int j = 0; j < 5; ++j)
#pragma unroll
        for (int r = 0; r < 16; ++r) acc[j][r] = 0.0f;

    // ---- helpers ----
    auto loadA = [&](int it, f32x4& v0, f32x4& v1) {
        int gk = it * 32 + skg * 8;
        const float* p = in + (size_t)(m0 + sm) * HID + gk;
        if (gk <= 292) { v0 = *(const f32x4*)p; v1 = *(const f32x4*)(p + 4); }
        else if (gk <= 296) { v0 = *(const f32x4*)p; v1 = f32x4{0.f,0.f,0.f,0.f}; }
        else { v0 = f32x4{0.f,0.f,0.f,0.f}; v1 = f32x4{0.f,0.f,0.f,0.f}; }
    };
    auto writeA = [&](int buf, const f32x4& v0, const f32x4& v1) {
        u32x4 pk;
        pk[0] = pack2(v0[0], v0[1]); pk[1] = pack2(v0[2], v0[3]);
        pk[2] = pack2(v1[0], v1[1]); pk[3] = pack2(v1[2], v1[3]);
        *(u32x4*)&As[buf][(skg >> 1) * 2048 + sm * 16 + (skg & 1) * 8] = pk;
    };
    auto stageB = [&](int buf, int it) {
        // 20 wave-instrs: i = w + 8*s -> c = i&3 (k8-chunk), ng = i>>2 (n/64)
#pragma unroll
        for (int s = 0; s < 3; ++s) {
            int i = w + 8 * s;
            if (i < 20) {
                int c = i & 3, ng = i >> 2;
                int n = ng * 64 + l;
                const u16* g = wihp + n * KP + it * 32 + c * 8;
                u16* d = &Bs[buf][c * 2560 + ng * 512];  // + lane*16B by HW
                __builtin_amdgcn_global_load_lds(
                    (const __attribute__((address_space(1))) void*)g,
                    (__attribute__((address_space(3))) void*)d, 16, 0, 0);
            }
        }
    };

    // ---- stage iter 0 ----
    {
        f32x4 v0, v1;
        loadA(0, v0, v1);
        writeA(0, v0, v1);
        stageB(0, 0);
    }
    __syncthreads();

#pragma unroll 1
    for (int it = 0; it < 10; ++it) {
        const int cb = it & 1, nb = (it + 1) & 1;
        f32x4 v0, v1;
        if (it < 9) {
            loadA(it + 1, v0, v1);   // global fp32 loads (prefetch)
            stageB(nb, it + 1);      // async global->LDS
        }
        // compute from buffer cb
#pragma unroll
        for (int s = 0; s < 2; ++s) {
            bf16x8 a = *(const bf16x8*)&As[cb][s * 2048 + mi * 512 + l31 * 16 + l5 * 8];
#pragma unroll
            for (int j = 0; j < 5; ++j) {
                bf16x8 b = *(const bf16x8*)&Bs[cb][(s * 2 + l5) * 2560 + ((ni * 5 + j) * 32 + l31) * 8];
                acc[j] = __builtin_amdgcn_mfma_f32_32x32x16_bf16(a, b, acc[j], 0, 0, 0);
            }
        }
        if (it < 9) writeA(nb, v0, v1);
        __syncthreads();
    }

    // epilogue: C(32x32): col = l&31 (n), row = (reg&3) + 8*(reg>>2) + 4*(l>>5)
    const int mbase = m0 + mi * 32;
#pragma unroll
    for (int j = 0; j < 5; ++j) {
        int n = (ni * 5 + j) * 32 + l31;
        if (n < HID) {
            float bs = bias[n];
#pragma unroll
            for (int reg = 0; reg < 16; ++reg) {
                int row = (reg & 3) + 8 * (reg >> 2) + 4 * l5;
                xp[(size_t)(mbase + row) * HID + n] = f2bf(acc[j][reg] + bs);
            }
        }
    }
}

// ---------------------------------------------------------------------------
// Phase 2: recurrence. 32 WGs x 256 thr (4 waves). Wave w owns N-tiles
// nt = w + 4*j, j=0..4 (20 tiles of 16 cover padded N=320).
// D[n][b]: A = W_hh (lane m=n=l&15, k=(l>>4)*8+j), B = h^T, C col=b,
// rows = 4 consecutive n. W_hh frags PINNED in registers (~200 VGPR/thread;
// 256 thr x 200 x 4B = exactly the 200 KB of padded W_hh, no duplication).
__global__ __launch_bounds__(256, 1) void rnn_recur_kernel(
    const u16* __restrict__ xp, const u16* __restrict__ whhp,
    float* __restrict__ out) {
    __shared__ __align__(16) u16 hb[2][16 * 328];   // double-buffered h

    const int tid = threadIdx.x;
    const int w = tid >> 6;            // wave 0..3
    const int l = tid & 63;
    const int br = l & 15;             // batch-rel
    const int q  = l >> 4;             // quad
    const int b0 = blockIdx.x * 16;

    // zero both h buffers (incl. padding)
    for (int i = tid; i < (2 * 16 * 328) / 2; i += 256) ((u32*)hb)[i] = 0;

    // W_hh A-fragments: load once, then make opaque so the compiler CANNOT
    // rematerialize them from global memory inside the t-loop (R2 bug:
    // it re-fetched all 50 frags from L2 every step -> L2-BW-bound).
    bf16x8 Af[5][10];
#pragma unroll
    for (int j = 0; j < 5; ++j) {
        const u16* wrow = whhp + (size_t)((w + 4 * j) * 16 + br) * KP;
#pragma unroll
        for (int ks = 0; ks < 10; ++ks)
            Af[j][ks] = *(const bf16x8*)(wrow + ks * 32 + q * 8);
    }
#pragma unroll
    for (int j = 0; j < 5; ++j)
#pragma unroll
        for (int ks = 0; ks < 10; ++ks)
            asm volatile("" : "+v"(Af[j][ks]));

    // xp element offsets (step-invariant part); -1 = padded column
    int xo[5];
#pragma unroll
    for (int j = 0; j < 5; ++j) {
        int n0 = (w + 4 * j) * 16 + q * 4;
        xo[j] = (n0 < HID) ? ((b0 + br) * HID + n0) : -1;
    }

    const s16x4 z4 = {0, 0, 0, 0};
    s16x4 xc[5], xn[5];
#pragma unroll
    for (int j = 0; j < 5; ++j) {
        xc[j] = (xo[j] >= 0) ? *(const s16x4*)(xp + xo[j]) : z4;
        xn[j] = (xo[j] >= 0) ? *(const s16x4*)(xp + (size_t)BZ * HID + xo[j]) : z4;
    }

    lds_barrier();

#pragma unroll 1
    for (int t = 0; t < SEQ; ++t) {
        const u16* hc = hb[t & 1];
        u16*       hn = hb[(t + 1) & 1];

        // prefetch xp for t+2 (never drained: raw barrier keeps vmcnt free)
        s16x4 xf[5];
        {
            int t2 = (t + 2 < SEQ) ? (t + 2) : (SEQ - 1);
            const u16* base = xp + (size_t)t2 * (BZ * HID);
#pragma unroll
            for (int j = 0; j < 5; ++j)
                xf[j] = (xo[j] >= 0) ? *(const s16x4*)(base + xo[j]) : z4;
        }

        f32x4 acc[5];
#pragma unroll
        for (int j = 0; j < 5; ++j)
#pragma unroll
            for (int r = 0; r < 4; ++r) acc[j][r] = 0.0f;

#pragma unroll
        for (int ks = 0; ks < 10; ++ks) {
            bf16x8 bfr = *(const bf16x8*)&hc[br * 328 + ks * 32 + q * 8];
#pragma unroll
            for (int j = 0; j < 5; ++j)
                acc[j] = __builtin_amdgcn_mfma_f32_16x16x32_bf16(Af[j][ks], bfr, acc[j], 0, 0, 0);
        }

        // h[b][n0..n0+3] = tanh(acc + xp), one b64 write per tile
#pragma unroll
        for (int j = 0; j < 5; ++j) {
            int n0 = (w + 4 * j) * 16 + q * 4;
            float v0 = tanh_fast(acc[j][0] + bf2f((u16)xc[j][0]));
            float v1 = tanh_fast(acc[j][1] + bf2f((u16)xc[j][1]));
            float v2 = tanh_fast(acc[j][2] + bf2f((u16)xc[j][2]));
            float v3 = tanh_fast(acc[j][3] + bf2f((u16)xc[j][3]));
            u32x2 pk;
            pk[0] = pack2(v0, v1);
            pk[1] = pack2(v2, v3);
            *(u32x2*)&hn[br * 328 + n0] = pk;
        }
        lds_barrier();   // LDS-only ordering; xp loads stay in flight

#pragma unroll
        for (int j = 0; j < 5; ++j) { xc[j] = xn[j]; xn[j] = xf[j]; }
    }

    // final h_512 lives in hb[0] (512 even)
    const u16* hf = hb[0];
    for (int i = tid; i < 16 * HID; i += 256) {
        int r = i / HID, n = i - r * HID;
        out[(size_t)(b0 + r) * HID + n] = bf2f(hf[r * 328 + n]);
    }
}

// ---------------------------------------------------------------------------
extern "C" void kernel_launch(void* const* d_in, const int* in_sizes, int n_in,
                              void* d_out, int out_size, void* d_ws, size_t ws_size,
                              hipStream_t stream) {
    const float* in  = (const float*)d_in[0];
    const float* wih = (const float*)d_in[1];
    const float* whh = (const float*)d_in[2];
    const float* bih = (const float*)d_in[3];
    const float* bhh = (const float*)d_in[4];

    char* ws = (char*)d_ws;
    const size_t XP_BYTES = (size_t)MTOT * HID * sizeof(u16);   // 157,286,400
    u16*   xpb  = (u16*)ws;
    u16*   wihp = (u16*)(ws + XP_BYTES);
    u16*   whhp = (u16*)(ws + XP_BYTES + (size_t)KP * KP * 2);
    float* bias = (float*)(ws + XP_BYTES + 2 * (size_t)KP * KP * 2);

    prep_kernel<<<KP, KP, 0, stream>>>(wih, whh, bih, bhh, wihp, whhp, bias);
    xproj_kernel<<<MTOT / 128, 512, 0, stream>>>(in, wihp, bias, xpb);
    rnn_recur_kernel<<<BZ / 16, 256, 0, stream>>>(xpb, whhp, (float*)d_out);
}

// Round 4
// 1134.841 us; speedup vs baseline: 1.0387x; 1.0387x over previous
//
#include <hip/hip_runtime.h>
#include <hip/hip_bf16.h>

// ---------------------------------------------------------------------------
// RNNCell encoder: seq=512, batch=512, H=IN=300.
//   prep:   W_ih, W_hh -> bf16 zero-padded [320][320]; bias = b_ih+b_hh.
//   xproj:  xp[m][n] = in[m][:]*W_ih[n][:] + bias[n]  (bf16 out, stride 300)
//           BM=128, BN=320, BK=32 double-buffered, 1 barrier/iter.
//   recur:  32 WGs x 256 thr. D[n][b] = W_hh * h^T orientation.
//           R4 KEY FIX: W_hh A-frags pinned into AGPRs ("a" constraint).
//           R2: compiler rematerialized global loads in-loop (144 VGPR).
//           R3: "+v" pin -> allocator spilled to scratch, SAME L2 traffic
//           (205 KB/WG/step / ~60 B/cy/CU = ~3400 cy/step = measured).
//           AGPRs: MFMA reads A directly from AGPR on gfx950 (unified RF),
//           VGPR side drops to ~90 -> nothing left to spill.
// ---------------------------------------------------------------------------

typedef unsigned short u16;
typedef unsigned int   u32;
typedef __attribute__((ext_vector_type(8)))  short bf16x8;
typedef __attribute__((ext_vector_type(4)))  short s16x4;
typedef __attribute__((ext_vector_type(4)))  float f32x4;
typedef __attribute__((ext_vector_type(16))) float f32x16;
typedef __attribute__((ext_vector_type(2)))  unsigned int u32x2;
typedef __attribute__((ext_vector_type(4)))  unsigned int u32x4;

#define HID 300
#define KP  320
#define SEQ 512
#define BZ  512
#define MTOT (SEQ*BZ)

__device__ __forceinline__ u16 f2bf(float f) {
    u32 u = __float_as_uint(f);
    return (u16)((u + 0x7FFFu + ((u >> 16) & 1u)) >> 16);  // RNE
}
__device__ __forceinline__ float bf2f(u16 h) {
    return __uint_as_float((u32)h << 16);
}
__device__ __forceinline__ float tanh_fast(float x) {
    float e = __builtin_amdgcn_exp2f(x * 2.8853900817779268f);  // exp(2x)
    float r = __builtin_amdgcn_rcpf(e + 1.0f);
    return __builtin_fmaf(-2.0f, r, 1.0f);
}
__device__ __forceinline__ u32 pack2(float a, float b) {
    __hip_bfloat162 t = __float22bfloat162_rn(float2{a, b});  // v_cvt_pk_bf16_f32
    return *(u32*)&t;
}
// Workgroup barrier WITHOUT vmcnt drain: LDS ordering only.
__device__ __forceinline__ void lds_barrier() {
    asm volatile("s_waitcnt lgkmcnt(0)\n\ts_barrier" ::: "memory");
}

// ---------------------------------------------------------------------------
__global__ void prep_kernel(const float* __restrict__ wih,
                            const float* __restrict__ whh,
                            const float* __restrict__ bih,
                            const float* __restrict__ bhh,
                            u16* __restrict__ wihp, u16* __restrict__ whhp,
                            float* __restrict__ bias) {
    int n = blockIdx.x, k = threadIdx.x;
    bool v = (n < HID) && (k < HID);
    int src = n * HID + k, dst = n * KP + k;
    wihp[dst] = v ? f2bf(wih[src]) : (u16)0;
    whhp[dst] = v ? f2bf(whh[src]) : (u16)0;
    if (k == 0) bias[n] = (n < HID) ? (bih[n] + bhh[n]) : 0.0f;
}

// ---------------------------------------------------------------------------
// Phase 1: xp = in @ W_ih^T + bias. 2048 WGs x 512 thr.
// LDS A layout (per buf): [kc16 0..1][m 0..127][16 el]   (4096 u16 = 8 KB)
// LDS B layout (per buf): [kc8 0..3][n 0..319][8 el]     (10240 u16 = 20 KB)
__global__ __launch_bounds__(512, 1) void xproj_kernel(
    const float* __restrict__ in, const u16* __restrict__ wihp,
    const float* __restrict__ bias, u16* __restrict__ xp) {
    __shared__ __align__(16) u16 As[2][4096];
    __shared__ __align__(16) u16 Bs[2][10240];

    const int tid = threadIdx.x;
    const int w = tid >> 6, l = tid & 63;
    const int mi = w & 3, ni = w >> 2;
    const int l31 = l & 31, l5 = l >> 5;
    const int m0 = blockIdx.x * 128;

    // staging roles
    const int sm = tid >> 2, skg = tid & 3;   // A: row, 8-k group

    f32x16 acc[5];
#pragma unroll
    for (int j = 0; j < 5; ++j)
#pragma unroll
        for (int r = 0; r < 16; ++r) acc[j][r] = 0.0f;

    // ---- helpers ----
    auto loadA = [&](int it, f32x4& v0, f32x4& v1) {
        int gk = it * 32 + skg * 8;
        const float* p = in + (size_t)(m0 + sm) * HID + gk;
        if (gk <= 292) { v0 = *(const f32x4*)p; v1 = *(const f32x4*)(p + 4); }
        else if (gk <= 296) { v0 = *(const f32x4*)p; v1 = f32x4{0.f,0.f,0.f,0.f}; }
        else { v0 = f32x4{0.f,0.f,0.f,0.f}; v1 = f32x4{0.f,0.f,0.f,0.f}; }
    };
    auto writeA = [&](int buf, const f32x4& v0, const f32x4& v1) {
        u32x4 pk;
        pk[0] = pack2(v0[0], v0[1]); pk[1] = pack2(v0[2], v0[3]);
        pk[2] = pack2(v1[0], v1[1]); pk[3] = pack2(v1[2], v1[3]);
        *(u32x4*)&As[buf][(skg >> 1) * 2048 + sm * 16 + (skg & 1) * 8] = pk;
    };
    auto stageB = [&](int buf, int it) {
#pragma unroll
        for (int s = 0; s < 3; ++s) {
            int i = w + 8 * s;
            if (i < 20) {
                int c = i & 3, ng = i >> 2;
                int n = ng * 64 + l;
                const u16* g = wihp + n * KP + it * 32 + c * 8;
                u16* d = &Bs[buf][c * 2560 + ng * 512];  // + lane*16B by HW
                __builtin_amdgcn_global_load_lds(
                    (const __attribute__((address_space(1))) void*)g,
                    (__attribute__((address_space(3))) void*)d, 16, 0, 0);
            }
        }
    };

    // ---- stage iter 0 ----
    {
        f32x4 v0, v1;
        loadA(0, v0, v1);
        writeA(0, v0, v1);
        stageB(0, 0);
    }
    __syncthreads();

#pragma unroll 1
    for (int it = 0; it < 10; ++it) {
        const int cb = it & 1, nb = (it + 1) & 1;
        f32x4 v0, v1;
        if (it < 9) {
            loadA(it + 1, v0, v1);   // global fp32 loads (prefetch)
            stageB(nb, it + 1);      // async global->LDS
        }
        // compute from buffer cb
#pragma unroll
        for (int s = 0; s < 2; ++s) {
            bf16x8 a = *(const bf16x8*)&As[cb][s * 2048 + mi * 512 + l31 * 16 + l5 * 8];
#pragma unroll
            for (int j = 0; j < 5; ++j) {
                bf16x8 b = *(const bf16x8*)&Bs[cb][(s * 2 + l5) * 2560 + ((ni * 5 + j) * 32 + l31) * 8];
                acc[j] = __builtin_amdgcn_mfma_f32_32x32x16_bf16(a, b, acc[j], 0, 0, 0);
            }
        }
        if (it < 9) writeA(nb, v0, v1);
        __syncthreads();
    }

    // epilogue: C(32x32): col = l&31 (n), row = (reg&3) + 8*(reg>>2) + 4*(l>>5)
    const int mbase = m0 + mi * 32;
#pragma unroll
    for (int j = 0; j < 5; ++j) {
        int n = (ni * 5 + j) * 32 + l31;
        if (n < HID) {
            float bs = bias[n];
#pragma unroll
            for (int reg = 0; reg < 16; ++reg) {
                int row = (reg & 3) + 8 * (reg >> 2) + 4 * l5;
                xp[(size_t)(mbase + row) * HID + n] = f2bf(acc[j][reg] + bs);
            }
        }
    }
}

// ---------------------------------------------------------------------------
// Phase 2: recurrence. 32 WGs x 256 thr (4 waves). Wave w owns N-tiles
// nt = w + 4*j, j=0..4. D[n][b]: A = W_hh, B = h^T, C col=b, rows = 4
// consecutive n. W_hh frags pinned in AGPRs (200/thread; 256 thr covers the
// full 200 KB padded W_hh exactly once).
__global__ __launch_bounds__(256, 1) void rnn_recur_kernel(
    const u16* __restrict__ xp, const u16* __restrict__ whhp,
    float* __restrict__ out) {
    __shared__ __align__(16) u16 hb[2][16 * 328];   // double-buffered h

    const int tid = threadIdx.x;
    const int w = tid >> 6;            // wave 0..3
    const int l = tid & 63;
    const int br = l & 15;             // batch-rel
    const int q  = l >> 4;             // quad
    const int b0 = blockIdx.x * 16;

    // zero both h buffers (incl. padding)
    for (int i = tid; i < (2 * 16 * 328) / 2; i += 256) ((u32*)hb)[i] = 0;

    // W_hh A-fragments: load once, pin into AGPRs. "+v" (R3) let the
    // allocator spill to scratch -> 205 KB/WG/step reloads. "a" places
    // them in the accumulator file, which MFMA reads directly as A.
    bf16x8 Af[5][10];
#pragma unroll
    for (int j = 0; j < 5; ++j) {
        const u16* wrow = whhp + (size_t)((w + 4 * j) * 16 + br) * KP;
#pragma unroll
        for (int ks = 0; ks < 10; ++ks)
            Af[j][ks] = *(const bf16x8*)(wrow + ks * 32 + q * 8);
    }
#pragma unroll
    for (int j = 0; j < 5; ++j)
#pragma unroll
        for (int ks = 0; ks < 10; ++ks)
            asm volatile("" : "+a"(Af[j][ks]));

    // xp element offsets (step-invariant part); -1 = padded column
    int xo[5];
#pragma unroll
    for (int j = 0; j < 5; ++j) {
        int n0 = (w + 4 * j) * 16 + q * 4;
        xo[j] = (n0 < HID) ? ((b0 + br) * HID + n0) : -1;
    }

    const s16x4 z4 = {0, 0, 0, 0};
    s16x4 xc[5], xn[5];
#pragma unroll
    for (int j = 0; j < 5; ++j) {
        xc[j] = (xo[j] >= 0) ? *(const s16x4*)(xp + xo[j]) : z4;
        xn[j] = (xo[j] >= 0) ? *(const s16x4*)(xp + (size_t)BZ * HID + xo[j]) : z4;
    }

    lds_barrier();

#pragma unroll 1
    for (int t = 0; t < SEQ; ++t) {
        const u16* hc = hb[t & 1];
        u16*       hn = hb[(t + 1) & 1];

        // prefetch xp for t+2 (raw barrier keeps vmcnt free -> stays in flight)
        s16x4 xf[5];
        {
            int t2 = (t + 2 < SEQ) ? (t + 2) : (SEQ - 1);
            const u16* base = xp + (size_t)t2 * (BZ * HID);
#pragma unroll
            for (int j = 0; j < 5; ++j)
                xf[j] = (xo[j] >= 0) ? *(const s16x4*)(base + xo[j]) : z4;
        }

        f32x4 acc[5];
#pragma unroll
        for (int j = 0; j < 5; ++j)
#pragma unroll
            for (int r = 0; r < 4; ++r) acc[j][r] = 0.0f;

#pragma unroll
        for (int ks = 0; ks < 10; ++ks) {
            bf16x8 bfr = *(const bf16x8*)&hc[br * 328 + ks * 32 + q * 8];
#pragma unroll
            for (int j = 0; j < 5; ++j)
                acc[j] = __builtin_amdgcn_mfma_f32_16x16x32_bf16(Af[j][ks], bfr, acc[j], 0, 0, 0);
        }

        // h[b][n0..n0+3] = tanh(acc + xp), one b64 write per tile
#pragma unroll
        for (int j = 0; j < 5; ++j) {
            int n0 = (w + 4 * j) * 16 + q * 4;
            float v0 = tanh_fast(acc[j][0] + bf2f((u16)xc[j][0]));
            float v1 = tanh_fast(acc[j][1] + bf2f((u16)xc[j][1]));
            float v2 = tanh_fast(acc[j][2] + bf2f((u16)xc[j][2]));
            float v3 = tanh_fast(acc[j][3] + bf2f((u16)xc[j][3]));
            u32x2 pk;
            pk[0] = pack2(v0, v1);
            pk[1] = pack2(v2, v3);
            *(u32x2*)&hn[br * 328 + n0] = pk;
        }
        lds_barrier();   // LDS-only ordering; xp loads stay in flight

#pragma unroll
        for (int j = 0; j < 5; ++j) { xc[j] = xn[j]; xn[j] = xf[j]; }
    }

    // final h_512 lives in hb[0] (512 even)
    const u16* hf = hb[0];
    for (int i = tid; i < 16 * HID; i += 256) {
        int r = i / HID, n = i - r * HID;
        out[(size_t)(b0 + r) * HID + n] = bf2f(hf[r * 328 + n]);
    }
}

// ---------------------------------------------------------------------------
extern "C" void kernel_launch(void* const* d_in, const int* in_sizes, int n_in,
                              void* d_out, int out_size, void* d_ws, size_t ws_size,
                              hipStream_t stream) {
    const float* in  = (const float*)d_in[0];
    const float* wih = (const float*)d_in[1];
    const float* whh = (const float*)d_in[2];
    const float* bih = (const float*)d_in[3];
    const float* bhh = (const float*)d_in[4];

    char* ws = (char*)d_ws;
    const size_t XP_BYTES = (size_t)MTOT * HID * sizeof(u16);   // 157,286,400
    u16*   xpb  = (u16*)ws;
    u16*   wihp = (u16*)(ws + XP_BYTES);
    u16*   whhp = (u16*)(ws + XP_BYTES + (size_t)KP * KP * 2);
    float* bias = (float*)(ws + XP_BYTES + 2 * (size_t)KP * KP * 2);

    prep_kernel<<<KP, KP, 0, stream>>>(wih, whh, bih, bhh, wihp, whhp, bias);
    xproj_kernel<<<MTOT / 128, 512, 0, stream>>>(in, wihp, bias, xpb);
    rnn_recur_kernel<<<BZ / 16, 256, 0, stream>>>(xpb, whhp, (float*)d_out);
}

// Round 5
// 1090.361 us; speedup vs baseline: 1.0810x; 1.0408x over previous
//
#include <hip/hip_runtime.h>
#include <hip/hip_bf16.h>

// ---------------------------------------------------------------------------
// RNNCell encoder: seq=512, batch=512, H=IN=300.
//   prep:   W_ih, W_hh -> bf16 zero-padded [320][320]; bias = b_ih+b_hh.
//   xproj:  xp[m][n] = in[m][:]*W_ih[n][:] + bias[n]  (bf16 out, stride 300)
//   recur:  32 WGs x 512 thr (8 waves). D[n][b] = W_hh * h^T orientation.
//           R5: tile split 3/3/3/3/2/2/2/2 over 20 N-tiles -> max 30 W-frags
//           = 120 AGPRs/thread (R2-R4 asked for 200 and the allocator spilled
//           ~205 KB/WG/step to scratch no matter how we pinned -> invariant
//           ~2860 cy/step). 120+~90 fits the 256-reg budget of (512,2);
//           2 waves/SIMD adds TLP. Per-CU MFMA work unchanged (~970 cy/step).
// ---------------------------------------------------------------------------

typedef unsigned short u16;
typedef unsigned int   u32;
typedef __attribute__((ext_vector_type(8)))  short bf16x8;
typedef __attribute__((ext_vector_type(4)))  short s16x4;
typedef __attribute__((ext_vector_type(4)))  float f32x4;
typedef __attribute__((ext_vector_type(16))) float f32x16;
typedef __attribute__((ext_vector_type(2)))  unsigned int u32x2;
typedef __attribute__((ext_vector_type(4)))  unsigned int u32x4;

#define HID 300
#define KP  320
#define SEQ 512
#define BZ  512
#define MTOT (SEQ*BZ)

__device__ __forceinline__ u16 f2bf(float f) {
    u32 u = __float_as_uint(f);
    return (u16)((u + 0x7FFFu + ((u >> 16) & 1u)) >> 16);  // RNE
}
__device__ __forceinline__ float bf2f(u16 h) {
    return __uint_as_float((u32)h << 16);
}
__device__ __forceinline__ float tanh_fast(float x) {
    float e = __builtin_amdgcn_exp2f(x * 2.8853900817779268f);  // exp(2x)
    float r = __builtin_amdgcn_rcpf(e + 1.0f);
    return __builtin_fmaf(-2.0f, r, 1.0f);
}
__device__ __forceinline__ u32 pack2(float a, float b) {
    __hip_bfloat162 t = __float22bfloat162_rn(float2{a, b});  // v_cvt_pk_bf16_f32
    return *(u32*)&t;
}
// Workgroup barrier WITHOUT vmcnt drain: LDS ordering only.
__device__ __forceinline__ void lds_barrier() {
    asm volatile("s_waitcnt lgkmcnt(0)\n\ts_barrier" ::: "memory");
}

// ---------------------------------------------------------------------------
__global__ void prep_kernel(const float* __restrict__ wih,
                            const float* __restrict__ whh,
                            const float* __restrict__ bih,
                            const float* __restrict__ bhh,
                            u16* __restrict__ wihp, u16* __restrict__ whhp,
                            float* __restrict__ bias) {
    int n = blockIdx.x, k = threadIdx.x;
    bool v = (n < HID) && (k < HID);
    int src = n * HID + k, dst = n * KP + k;
    wihp[dst] = v ? f2bf(wih[src]) : (u16)0;
    whhp[dst] = v ? f2bf(whh[src]) : (u16)0;
    if (k == 0) bias[n] = (n < HID) ? (bih[n] + bhh[n]) : 0.0f;
}

// ---------------------------------------------------------------------------
// Phase 1: xp = in @ W_ih^T + bias. 2048 WGs x 512 thr. (unchanged from R4)
__global__ __launch_bounds__(512, 1) void xproj_kernel(
    const float* __restrict__ in, const u16* __restrict__ wihp,
    const float* __restrict__ bias, u16* __restrict__ xp) {
    __shared__ __align__(16) u16 As[2][4096];
    __shared__ __align__(16) u16 Bs[2][10240];

    const int tid = threadIdx.x;
    const int w = tid >> 6, l = tid & 63;
    const int mi = w & 3, ni = w >> 2;
    const int l31 = l & 31, l5 = l >> 5;
    const int m0 = blockIdx.x * 128;

    const int sm = tid >> 2, skg = tid & 3;   // A staging: row, 8-k group

    f32x16 acc[5];
#pragma unroll
    for (int j = 0; j < 5; ++j)
#pragma unroll
        for (int r = 0; r < 16; ++r) acc[j][r] = 0.0f;

    auto loadA = [&](int it, f32x4& v0, f32x4& v1) {
        int gk = it * 32 + skg * 8;
        const float* p = in + (size_t)(m0 + sm) * HID + gk;
        if (gk <= 292) { v0 = *(const f32x4*)p; v1 = *(const f32x4*)(p + 4); }
        else if (gk <= 296) { v0 = *(const f32x4*)p; v1 = f32x4{0.f,0.f,0.f,0.f}; }
        else { v0 = f32x4{0.f,0.f,0.f,0.f}; v1 = f32x4{0.f,0.f,0.f,0.f}; }
    };
    auto writeA = [&](int buf, const f32x4& v0, const f32x4& v1) {
        u32x4 pk;
        pk[0] = pack2(v0[0], v0[1]); pk[1] = pack2(v0[2], v0[3]);
        pk[2] = pack2(v1[0], v1[1]); pk[3] = pack2(v1[2], v1[3]);
        *(u32x4*)&As[buf][(skg >> 1) * 2048 + sm * 16 + (skg & 1) * 8] = pk;
    };
    auto stageB = [&](int buf, int it) {
#pragma unroll
        for (int s = 0; s < 3; ++s) {
            int i = w + 8 * s;
            if (i < 20) {
                int c = i & 3, ng = i >> 2;
                int n = ng * 64 + l;
                const u16* g = wihp + n * KP + it * 32 + c * 8;
                u16* d = &Bs[buf][c * 2560 + ng * 512];
                __builtin_amdgcn_global_load_lds(
                    (const __attribute__((address_space(1))) void*)g,
                    (__attribute__((address_space(3))) void*)d, 16, 0, 0);
            }
        }
    };

    {
        f32x4 v0, v1;
        loadA(0, v0, v1);
        writeA(0, v0, v1);
        stageB(0, 0);
    }
    __syncthreads();

#pragma unroll 1
    for (int it = 0; it < 10; ++it) {
        const int cb = it & 1, nb = (it + 1) & 1;
        f32x4 v0, v1;
        if (it < 9) {
            loadA(it + 1, v0, v1);
            stageB(nb, it + 1);
        }
#pragma unroll
        for (int s = 0; s < 2; ++s) {
            bf16x8 a = *(const bf16x8*)&As[cb][s * 2048 + mi * 512 + l31 * 16 + l5 * 8];
#pragma unroll
            for (int j = 0; j < 5; ++j) {
                bf16x8 b = *(const bf16x8*)&Bs[cb][(s * 2 + l5) * 2560 + ((ni * 5 + j) * 32 + l31) * 8];
                acc[j] = __builtin_amdgcn_mfma_f32_32x32x16_bf16(a, b, acc[j], 0, 0, 0);
            }
        }
        if (it < 9) writeA(nb, v0, v1);
        __syncthreads();
    }

    const int mbase = m0 + mi * 32;
#pragma unroll
    for (int j = 0; j < 5; ++j) {
        int n = (ni * 5 + j) * 32 + l31;
        if (n < HID) {
            float bs = bias[n];
#pragma unroll
            for (int reg = 0; reg < 16; ++reg) {
                int row = (reg & 3) + 8 * (reg >> 2) + 4 * l5;
                xp[(size_t)(mbase + row) * HID + n] = f2bf(acc[j][reg] + bs);
            }
        }
    }
}

// ---------------------------------------------------------------------------
// Phase 2: recurrence. 32 WGs x 512 thr (8 waves). Wave w owns N-tiles
// {w, w+8, w+16<only w<4>} of 20. D[n][b]: A = W_hh (lane m=n), B = h^T,
// C col = b, rows = 4 consecutive n. Max 30 W-frags = 120 AGPR/thread.
__global__ __launch_bounds__(512, 2) void rnn_recur_kernel(
    const u16* __restrict__ xp, const u16* __restrict__ whhp,
    float* __restrict__ out) {
    __shared__ __align__(16) u16 hb[2][16 * 328];   // double-buffered h

    const int tid = threadIdx.x;
    const int w = tid >> 6;            // wave 0..7
    const int l = tid & 63;
    const int br = l & 15;             // batch-rel (B col / C col)
    const int q  = l >> 4;             // quad
    const int b0 = blockIdx.x * 16;
    const bool t3 = (w < 4);           // waves 0-3 own a third tile

    // zero both h buffers (incl. padding)
    for (int i = tid; i < (2 * 16 * 328) / 2; i += 512) ((u32*)hb)[i] = 0;

    // W_hh A-fragments (load once; pinned to AGPRs)
    bf16x8 Af[3][10];
#pragma unroll
    for (int j = 0; j < 3; ++j) {
        if (j < 2 || t3) {
            const int nt = w + 8 * j;
            const u16* wrow = whhp + (size_t)(nt * 16 + br) * KP;
#pragma unroll
            for (int ks = 0; ks < 10; ++ks)
                Af[j][ks] = *(const bf16x8*)(wrow + ks * 32 + q * 8);
        }
    }
#pragma unroll
    for (int j = 0; j < 3; ++j)
        if (j < 2 || t3)
#pragma unroll
            for (int ks = 0; ks < 10; ++ks)
                asm volatile("" : "+a"(Af[j][ks]));

    // xp element offsets (step-invariant); -1 = fully-padded quad
    int xo[3];
#pragma unroll
    for (int j = 0; j < 3; ++j) {
        int n0 = (w + 8 * j) * 16 + q * 4;
        xo[j] = (n0 < HID && (j < 2 || t3)) ? ((b0 + br) * HID + n0) : -1;
    }

    const s16x4 z4 = {0, 0, 0, 0};
    s16x4 xc[3], xn[3];
#pragma unroll
    for (int j = 0; j < 3; ++j) {
        xc[j] = (xo[j] >= 0) ? *(const s16x4*)(xp + xo[j]) : z4;
        xn[j] = (xo[j] >= 0) ? *(const s16x4*)(xp + (size_t)BZ * HID + xo[j]) : z4;
    }

    lds_barrier();

#pragma unroll 1
    for (int t = 0; t < SEQ; ++t) {
        const u16* hc = hb[t & 1];
        u16*       hn = hb[(t + 1) & 1];

        // prefetch xp for t+2 (raw barrier keeps vmcnt free -> stays in flight)
        s16x4 xf[3];
        {
            int t2 = (t + 2 < SEQ) ? (t + 2) : (SEQ - 1);
            const u16* base = xp + (size_t)t2 * (BZ * HID);
#pragma unroll
            for (int j = 0; j < 3; ++j)
                xf[j] = (xo[j] >= 0) ? *(const s16x4*)(base + xo[j]) : z4;
        }

        f32x4 a0, a1, a2;
#pragma unroll
        for (int r = 0; r < 4; ++r) { a0[r] = 0.f; a1[r] = 0.f; a2[r] = 0.f; }

#pragma unroll
        for (int ks = 0; ks < 10; ++ks) {
            bf16x8 bfr = *(const bf16x8*)&hc[br * 328 + ks * 32 + q * 8];
            a0 = __builtin_amdgcn_mfma_f32_16x16x32_bf16(Af[0][ks], bfr, a0, 0, 0, 0);
            a1 = __builtin_amdgcn_mfma_f32_16x16x32_bf16(Af[1][ks], bfr, a1, 0, 0, 0);
            if (t3)
                a2 = __builtin_amdgcn_mfma_f32_16x16x32_bf16(Af[2][ks], bfr, a2, 0, 0, 0);
        }

        // h[b][n0..n0+3] = tanh(acc + xp); pad cols: acc=0, xc=0 -> tanh(0)=0
        {
            int n0 = w * 16 + q * 4;
            u32x2 pk;
            pk[0] = pack2(tanh_fast(a0[0] + bf2f((u16)xc[0][0])),
                          tanh_fast(a0[1] + bf2f((u16)xc[0][1])));
            pk[1] = pack2(tanh_fast(a0[2] + bf2f((u16)xc[0][2])),
                          tanh_fast(a0[3] + bf2f((u16)xc[0][3])));
            *(u32x2*)&hn[br * 328 + n0] = pk;
        }
        {
            int n0 = (w + 8) * 16 + q * 4;
            u32x2 pk;
            pk[0] = pack2(tanh_fast(a1[0] + bf2f((u16)xc[1][0])),
                          tanh_fast(a1[1] + bf2f((u16)xc[1][1])));
            pk[1] = pack2(tanh_fast(a1[2] + bf2f((u16)xc[1][2])),
                          tanh_fast(a1[3] + bf2f((u16)xc[1][3])));
            *(u32x2*)&hn[br * 328 + n0] = pk;
        }
        if (t3) {
            int n0 = (w + 16) * 16 + q * 4;
            u32x2 pk;
            pk[0] = pack2(tanh_fast(a2[0] + bf2f((u16)xc[2][0])),
                          tanh_fast(a2[1] + bf2f((u16)xc[2][1])));
            pk[1] = pack2(tanh_fast(a2[2] + bf2f((u16)xc[2][2])),
                          tanh_fast(a2[3] + bf2f((u16)xc[2][3])));
            *(u32x2*)&hn[br * 328 + n0] = pk;
        }
        lds_barrier();   // LDS-only ordering; xp loads stay in flight

#pragma unroll
        for (int j = 0; j < 3; ++j) { xc[j] = xn[j]; xn[j] = xf[j]; }
    }

    // final h_512 lives in hb[0] (512 even)
    const u16* hf = hb[0];
    for (int i = tid; i < 16 * HID; i += 512) {
        int r = i / HID, n = i - r * HID;
        out[(size_t)(b0 + r) * HID + n] = bf2f(hf[r * 328 + n]);
    }
}

// ---------------------------------------------------------------------------
extern "C" void kernel_launch(void* const* d_in, const int* in_sizes, int n_in,
                              void* d_out, int out_size, void* d_ws, size_t ws_size,
                              hipStream_t stream) {
    const float* in  = (const float*)d_in[0];
    const float* wih = (const float*)d_in[1];
    const float* whh = (const float*)d_in[2];
    const float* bih = (const float*)d_in[3];
    const float* bhh = (const float*)d_in[4];

    char* ws = (char*)d_ws;
    const size_t XP_BYTES = (size_t)MTOT * HID * sizeof(u16);   // 157,286,400
    u16*   xpb  = (u16*)ws;
    u16*   wihp = (u16*)(ws + XP_BYTES);
    u16*   whhp = (u16*)(ws + XP_BYTES + (size_t)KP * KP * 2);
    float* bias = (float*)(ws + XP_BYTES + 2 * (size_t)KP * KP * 2);

    prep_kernel<<<KP, KP, 0, stream>>>(wih, whh, bih, bhh, wihp, whhp, bias);
    xproj_kernel<<<MTOT / 128, 512, 0, stream>>>(in, wihp, bias, xpb);
    rnn_recur_kernel<<<BZ / 16, 512, 0, stream>>>(xpb, whhp, (float*)d_out);
}